// Round 1
// baseline (2111.001 us; speedup 1.0000x reference)
//
#include <hip/hip_runtime.h>
#include <hip/hip_bf16.h>

#define VOCAB 29
#define VEC   512
#define HID   1024
#define SEN   64
#define BATCH 2048

typedef __bf16 bf16_t;
typedef bf16_t bf16x8 __attribute__((ext_vector_type(8)));
typedef float  floatx4 __attribute__((ext_vector_type(4)));

// ---------------- kernel 1: W_hh fp32 -> bf16 ----------------
__global__ void cvt_whh(const float* __restrict__ w, bf16_t* __restrict__ o, int n) {
    int i = blockIdx.x * blockDim.x + threadIdx.x;
    if (i < n) o[i] = (bf16_t)w[i];
}

// ---------------- kernel 2: proj[v][h] = dot(emb[v], W_ih[h]) (fp32) ----------------
__global__ void proj_kernel(const float* __restrict__ emb, const float* __restrict__ wih,
                            float* __restrict__ proj) {
    int idx = blockIdx.x * blockDim.x + threadIdx.x;
    if (idx >= VOCAB * HID) return;
    int v = idx / HID, h = idx % HID;
    const float* e = emb + v * VEC;
    const float* w = wih + h * VEC;
    float s = 0.f;
    for (int k = 0; k < VEC; k += 4) {
        float4 ev = *(const float4*)(e + k);
        float4 wv = *(const float4*)(w + k);
        s += ev.x * wv.x + ev.y * wv.y + ev.z * wv.z + ev.w * wv.w;
    }
    proj[idx] = s;
}

// ---------------- kernel 3: one RNN step ----------------
// h_out[b,i] = tanh( proj[x[b,t]][i] + sum_j h_in[b,j] * W_hh[i,j] )
// C = A * B^T pattern: A = h_in [2048,1024] bf16 row-major, B = W_hh [1024,1024] bf16 row-major.
#define BM 128
#define BN 128
#define BK 64
#define LDK (BK + 8)   // +8 bf16 = +16B pad: breaks the 32-dword bank stride

__global__ __launch_bounds__(256)
void rnn_step(const bf16_t* __restrict__ h_in, const bf16_t* __restrict__ whh,
              const float* __restrict__ proj, const int* __restrict__ x,
              bf16_t* __restrict__ h_out, int t, int first)
{
    __shared__ bf16_t Ash[BM][LDK];
    __shared__ bf16_t Bsh[BN][LDK];
    __shared__ int tok_sh[BM];

    const int tid = threadIdx.x;
    const int m0 = blockIdx.x * BM;
    const int n0 = blockIdx.y * BN;

    if (tid < BM) tok_sh[tid] = x[(m0 + tid) * SEN + t];

    const int wave = tid >> 6;
    const int lane = tid & 63;
    const int wm = (wave >> 1) * 64;   // wave m-offset in block tile
    const int wn = (wave & 1) * 64;    // wave n-offset
    const int q   = lane >> 4;         // quad 0..3
    const int l16 = lane & 15;

    floatx4 acc[4][4];
#pragma unroll
    for (int i = 0; i < 4; i++)
#pragma unroll
        for (int j = 0; j < 4; j++) acc[i][j] = (floatx4){0.f, 0.f, 0.f, 0.f};

    const int kend = first ? 0 : HID;
    for (int kk = 0; kk < kend; kk += BK) {
        // stage A tile: 128 rows x 64 cols bf16 -> 1024 x 16B loads, 4 per thread
#pragma unroll
        for (int it = 0; it < 4; it++) {
            int idx = tid + it * 256;
            int r = idx >> 3, c = (idx & 7) * 8;
            *(uint4*)&Ash[r][c] = *(const uint4*)&h_in[(m0 + r) * HID + kk + c];
        }
#pragma unroll
        for (int it = 0; it < 4; it++) {
            int idx = tid + it * 256;
            int r = idx >> 3, c = (idx & 7) * 8;
            *(uint4*)&Bsh[r][c] = *(const uint4*)&whh[(n0 + r) * HID + kk + c];
        }
        __syncthreads();
#pragma unroll
        for (int ks = 0; ks < BK; ks += 32) {
            bf16x8 af[4], bfr[4];
#pragma unroll
            for (int mi = 0; mi < 4; mi++)
                af[mi] = *(const bf16x8*)&Ash[wm + mi * 16 + l16][ks + q * 8];
#pragma unroll
            for (int ni = 0; ni < 4; ni++)
                bfr[ni] = *(const bf16x8*)&Bsh[wn + ni * 16 + l16][ks + q * 8];
#pragma unroll
            for (int mi = 0; mi < 4; mi++)
#pragma unroll
                for (int ni = 0; ni < 4; ni++)
                    acc[mi][ni] = __builtin_amdgcn_mfma_f32_16x16x32_bf16(
                        af[mi], bfr[ni], acc[mi][ni], 0, 0, 0);
        }
        __syncthreads();
    }
    __syncthreads();  // covers tok_sh visibility (incl. first==1 path)

    // epilogue: C/D frag mapping: row = q*4 + reg, col = lane&15
#pragma unroll
    for (int mi = 0; mi < 4; mi++) {
#pragma unroll
        for (int r = 0; r < 4; r++) {
            int lm = wm + mi * 16 + q * 4 + r;
            int gm = m0 + lm;
            const float* pr = proj + tok_sh[lm] * HID;
#pragma unroll
            for (int ni = 0; ni < 4; ni++) {
                int gn = n0 + wn + ni * 16 + l16;
                float v = acc[mi][ni][r] + pr[gn];
                h_out[gm * HID + gn] = (bf16_t)tanhf(v);
            }
        }
    }
}

// ---------------- kernel 4: logits = h @ W_cls^T + b_cls ----------------
__global__ __launch_bounds__(256)
void classifier(const bf16_t* __restrict__ h, const float* __restrict__ wcls,
                const float* __restrict__ bcls, float* __restrict__ out)
{
    int wave = threadIdx.x >> 6, lane = threadIdx.x & 63;
    int b = blockIdx.x * 4 + wave;
    float hf[16];
    const bf16_t* hp = h + b * HID + lane * 16;
#pragma unroll
    for (int u = 0; u < 16; u++) hf[u] = (float)hp[u];
    for (int c = 0; c <= SEN; c++) {
        const float* w = wcls + c * HID + lane * 16;
        float s = 0.f;
#pragma unroll
        for (int u = 0; u < 16; u += 4) {
            float4 wv = *(const float4*)(w + u);
            s += hf[u] * wv.x + hf[u + 1] * wv.y + hf[u + 2] * wv.z + hf[u + 3] * wv.w;
        }
#pragma unroll
        for (int off = 32; off; off >>= 1) s += __shfl_down(s, off);
        if (lane == 0) out[b * (SEN + 1) + c] = s + bcls[c];
    }
}

extern "C" void kernel_launch(void* const* d_in, const int* in_sizes, int n_in,
                              void* d_out, int out_size, void* d_ws, size_t ws_size,
                              hipStream_t stream)
{
    const int*   x     = (const int*)  d_in[0];
    const float* emb   = (const float*)d_in[1];
    const float* w_ih  = (const float*)d_in[2];
    const float* w_hh  = (const float*)d_in[3];
    const float* w_cls = (const float*)d_in[4];
    const float* b_cls = (const float*)d_in[5];
    float* out = (float*)d_out;

    char* ws = (char*)d_ws;
    bf16_t* whh_bf = (bf16_t*)ws;                                   // 2 MB
    float*  proj   = (float*)(ws + (2u << 20));                     // 128 KB
    bf16_t* h0     = (bf16_t*)(ws + (2u << 20) + (128u << 10));     // 4 MB
    bf16_t* h1     = (bf16_t*)(ws + (2u << 20) + (128u << 10) + (4u << 20)); // 4 MB

    cvt_whh<<<(HID * HID) / 256, 256, 0, stream>>>(w_hh, whh_bf, HID * HID);
    proj_kernel<<<(VOCAB * HID + 255) / 256, 256, 0, stream>>>(emb, w_ih, proj);

    dim3 grid(BATCH / BM, HID / BN);
    bf16_t* bufs[2] = {h0, h1};
    for (int t = 0; t < SEN; t++) {
        bf16_t* hi = bufs[(t + 1) & 1];   // ignored when t==0 (first=1)
        bf16_t* ho = bufs[t & 1];
        rnn_step<<<grid, 256, 0, stream>>>(hi, whh_bf, proj, x, ho, t, t == 0 ? 1 : 0);
    }
    classifier<<<BATCH / 4, 256, 0, stream>>>(bufs[1], w_cls, b_cls, out);
}

// Round 2
// 1200.079 us; speedup vs baseline: 1.7591x; 1.7591x over previous
//
#include <hip/hip_runtime.h>
#include <hip/hip_bf16.h>

#define VOCAB 29
#define VEC   512
#define HID   1024
#define SEN   64
#define BATCH 2048

typedef __bf16 bf16_t;
typedef bf16_t bf16x8 __attribute__((ext_vector_type(8)));
typedef float  floatx4 __attribute__((ext_vector_type(4)));

// ---------------- prep: W_hh fp32 -> bf16 ----------------
__global__ void cvt_whh(const float* __restrict__ w, bf16_t* __restrict__ o, int n) {
    int i = blockIdx.x * blockDim.x + threadIdx.x;
    if (i < n) o[i] = (bf16_t)w[i];
}

// ---------------- prep: W_cls fp32 [65][1024] -> bf16 padded [80][1024] ----------------
__global__ void cvt_wcls(const float* __restrict__ w, bf16_t* __restrict__ o) {
    int i = blockIdx.x * blockDim.x + threadIdx.x;
    if (i >= 80 * HID) return;
    o[i] = (i < 65 * HID) ? (bf16_t)w[i] : (bf16_t)0.0f;
}

// ---------------- prep: proj[v][h] = dot(emb[v], W_ih[h]) (fp32) ----------------
__global__ void proj_kernel(const float* __restrict__ emb, const float* __restrict__ wih,
                            float* __restrict__ proj) {
    int idx = blockIdx.x * blockDim.x + threadIdx.x;
    if (idx >= VOCAB * HID) return;
    int v = idx / HID, h = idx % HID;
    const float* e = emb + v * VEC;
    const float* w = wih + h * VEC;
    float s = 0.f;
    for (int k = 0; k < VEC; k += 4) {
        float4 ev = *(const float4*)(e + k);
        float4 wv = *(const float4*)(w + k);
        s += ev.x * wv.x + ev.y * wv.y + ev.z * wv.z + ev.w * wv.w;
    }
    proj[idx] = s;
}

// ---------------- RNN step: h_out = tanh(proj[x[:,t]] + h_in @ W_hh^T) ----------------
// BM=128, BN=64 -> grid (16,16)=256 blocks: one per CU.
// 4 waves, wave tile 32(m) x 64(n) of 16x16x32 bf16 frags (verified layout).
// Double-buffered LDS + VGPR prefetch, ONE barrier per K-iter.
#define BM 128
#define BN 64
#define BK 64
#define LDK 72   // 144B row stride: 16B-aligned rows, breaks 32-dword bank overlay

__global__ __launch_bounds__(256)
void rnn_step(const bf16_t* __restrict__ h_in, const bf16_t* __restrict__ whh,
              const float* __restrict__ proj, const int* __restrict__ x,
              bf16_t* __restrict__ h_out, int t, int first)
{
    __shared__ __align__(16) bf16_t Ash[2][BM][LDK];
    __shared__ __align__(16) bf16_t Bsh[2][BN][LDK];
    __shared__ int tok_sh[BM];

    const int tid = threadIdx.x;
    const int m0 = blockIdx.x * BM;
    const int n0 = blockIdx.y * BN;
    if (tid < BM) tok_sh[tid] = x[(m0 + tid) * SEN + t];

    const int wave = tid >> 6;
    const int lane = tid & 63;
    const int wm   = wave * 32;        // wave m-offset (4 waves split m)
    const int q    = lane >> 4;        // quad 0..3
    const int l16  = lane & 15;

    floatx4 acc[2][4];
#pragma unroll
    for (int i = 0; i < 2; i++)
#pragma unroll
        for (int j = 0; j < 4; j++) acc[i][j] = (floatx4){0.f, 0.f, 0.f, 0.f};

    // per-thread staging coordinates (A: 4 chunks, B: 2 chunks of 16B)
    if (!first) {
        // stage tile 0 -> buf 0
#pragma unroll
        for (int it = 0; it < 4; it++) {
            int idx = tid + it * 256, r = idx >> 3, c = (idx & 7) * 8;
            *(uint4*)&Ash[0][r][c] = *(const uint4*)&h_in[(m0 + r) * HID + c];
        }
#pragma unroll
        for (int it = 0; it < 2; it++) {
            int idx = tid + it * 256, r = idx >> 3, c = (idx & 7) * 8;
            *(uint4*)&Bsh[0][r][c] = *(const uint4*)&whh[(n0 + r) * HID + c];
        }
    }
    __syncthreads();   // covers tok_sh (all paths) + tile-0 staging

    if (!first) {
        for (int i = 0; i < 16; i++) {
            const int buf = i & 1;
            uint4 pa[4], pb[2];
            const int kk = (i + 1) * BK;
            if (i < 15) {   // issue prefetch BEFORE compute: latency overlaps MFMA phase
#pragma unroll
                for (int it = 0; it < 4; it++) {
                    int idx = tid + it * 256, r = idx >> 3, c = (idx & 7) * 8;
                    pa[it] = *(const uint4*)&h_in[(m0 + r) * HID + kk + c];
                }
#pragma unroll
                for (int it = 0; it < 2; it++) {
                    int idx = tid + it * 256, r = idx >> 3, c = (idx & 7) * 8;
                    pb[it] = *(const uint4*)&whh[(n0 + r) * HID + kk + c];
                }
            }
#pragma unroll
            for (int ks = 0; ks < BK; ks += 32) {
                bf16x8 af[2], bfr[4];
#pragma unroll
                for (int mi = 0; mi < 2; mi++)
                    af[mi] = *(const bf16x8*)&Ash[buf][wm + mi * 16 + l16][ks + q * 8];
#pragma unroll
                for (int ni = 0; ni < 4; ni++)
                    bfr[ni] = *(const bf16x8*)&Bsh[buf][ni * 16 + l16][ks + q * 8];
#pragma unroll
                for (int mi = 0; mi < 2; mi++)
#pragma unroll
                    for (int ni = 0; ni < 4; ni++)
                        acc[mi][ni] = __builtin_amdgcn_mfma_f32_16x16x32_bf16(
                            af[mi], bfr[ni], acc[mi][ni], 0, 0, 0);
            }
            if (i < 15) {
#pragma unroll
                for (int it = 0; it < 4; it++) {
                    int idx = tid + it * 256, r = idx >> 3, c = (idx & 7) * 8;
                    *(uint4*)&Ash[1 - buf][r][c] = pa[it];
                }
#pragma unroll
                for (int it = 0; it < 2; it++) {
                    int idx = tid + it * 256, r = idx >> 3, c = (idx & 7) * 8;
                    *(uint4*)&Bsh[1 - buf][r][c] = pb[it];
                }
                __syncthreads();   // single barrier per iter (dbuf makes it safe)
            }
        }
    }

    // epilogue: C/D mapping row = q*4 + reg, col = lane&15 (HW-verified)
#pragma unroll
    for (int mi = 0; mi < 2; mi++) {
#pragma unroll
        for (int r = 0; r < 4; r++) {
            int lm = wm + mi * 16 + q * 4 + r;
            int gm = m0 + lm;
            const float* pr = proj + tok_sh[lm] * HID;
#pragma unroll
            for (int ni = 0; ni < 4; ni++) {
                int gn = n0 + ni * 16 + l16;
                float v = acc[mi][ni][r] + pr[gn];
                h_out[gm * HID + gn] = (bf16_t)tanhf(v);
            }
        }
    }
}

// ---------------- classifier: out = h @ W_cls^T + b_cls via MFMA ----------------
// BM=128, N padded to 80 (5 n-frags). Grid = 16 blocks. Simple single-buffered loop.
__global__ __launch_bounds__(256)
void classifier_mfma(const bf16_t* __restrict__ h, const bf16_t* __restrict__ wcls,
                     const float* __restrict__ bcls, float* __restrict__ out)
{
    __shared__ __align__(16) bf16_t Ash[BM][LDK];
    __shared__ __align__(16) bf16_t Bsh[80][LDK];

    const int tid = threadIdx.x;
    const int m0 = blockIdx.x * BM;
    const int wave = tid >> 6, lane = tid & 63;
    const int wm = wave * 32;
    const int q = lane >> 4, l16 = lane & 15;

    floatx4 acc[2][5];
#pragma unroll
    for (int i = 0; i < 2; i++)
#pragma unroll
        for (int j = 0; j < 5; j++) acc[i][j] = (floatx4){0.f, 0.f, 0.f, 0.f};

    for (int kk = 0; kk < HID; kk += BK) {
#pragma unroll
        for (int it = 0; it < 4; it++) {
            int idx = tid + it * 256, r = idx >> 3, c = (idx & 7) * 8;
            *(uint4*)&Ash[r][c] = *(const uint4*)&h[(m0 + r) * HID + kk + c];
        }
#pragma unroll
        for (int it = 0; it < 3; it++) {
            int idx = tid + it * 256;
            if (idx < 640) {
                int r = idx >> 3, c = (idx & 7) * 8;
                *(uint4*)&Bsh[r][c] = *(const uint4*)&wcls[r * HID + kk + c];
            }
        }
        __syncthreads();
#pragma unroll
        for (int ks = 0; ks < BK; ks += 32) {
            bf16x8 af[2], bfr[5];
#pragma unroll
            for (int mi = 0; mi < 2; mi++)
                af[mi] = *(const bf16x8*)&Ash[wm + mi * 16 + l16][ks + q * 8];
#pragma unroll
            for (int ni = 0; ni < 5; ni++)
                bfr[ni] = *(const bf16x8*)&Bsh[ni * 16 + l16][ks + q * 8];
#pragma unroll
            for (int mi = 0; mi < 2; mi++)
#pragma unroll
                for (int ni = 0; ni < 5; ni++)
                    acc[mi][ni] = __builtin_amdgcn_mfma_f32_16x16x32_bf16(
                        af[mi], bfr[ni], acc[mi][ni], 0, 0, 0);
        }
        __syncthreads();
    }

#pragma unroll
    for (int mi = 0; mi < 2; mi++) {
#pragma unroll
        for (int r = 0; r < 4; r++) {
            int gm = m0 + wm + mi * 16 + q * 4 + r;
#pragma unroll
            for (int ni = 0; ni < 5; ni++) {
                int gn = ni * 16 + l16;
                if (gn < SEN + 1)
                    out[gm * (SEN + 1) + gn] = acc[mi][ni][r] + bcls[gn];
            }
        }
    }
}

extern "C" void kernel_launch(void* const* d_in, const int* in_sizes, int n_in,
                              void* d_out, int out_size, void* d_ws, size_t ws_size,
                              hipStream_t stream)
{
    const int*   x     = (const int*)  d_in[0];
    const float* emb   = (const float*)d_in[1];
    const float* w_ih  = (const float*)d_in[2];
    const float* w_hh  = (const float*)d_in[3];
    const float* w_cls = (const float*)d_in[4];
    const float* b_cls = (const float*)d_in[5];
    float* out = (float*)d_out;

    char* ws = (char*)d_ws;
    bf16_t* whh_bf  = (bf16_t*)ws;                                  // 2 MB
    float*  proj    = (float*)(ws + (2u << 20));                    // 128 KB
    bf16_t* wcls_bf = (bf16_t*)(ws + (2u << 20) + (128u << 10));    // 160 KB
    bf16_t* h0      = (bf16_t*)(ws + (2u << 20) + (288u << 10));    // 4 MB
    bf16_t* h1      = (bf16_t*)(ws + (6u << 20) + (288u << 10));    // 4 MB

    cvt_whh<<<(HID * HID) / 256, 256, 0, stream>>>(w_hh, whh_bf, HID * HID);
    proj_kernel<<<(VOCAB * HID + 255) / 256, 256, 0, stream>>>(emb, w_ih, proj);
    cvt_wcls<<<(80 * HID) / 256, 256, 0, stream>>>(w_cls, wcls_bf);

    dim3 grid(BATCH / BM, HID / BN);   // (16,16) = 256 blocks
    bf16_t* bufs[2] = {h0, h1};
    for (int t = 0; t < SEN; t++) {
        bf16_t* hi = bufs[(t + 1) & 1];   // ignored when t==0 (first=1)
        bf16_t* ho = bufs[t & 1];
        rnn_step<<<grid, 256, 0, stream>>>(hi, whh_bf, proj, x, ho, t, t == 0 ? 1 : 0);
    }
    classifier_mfma<<<BATCH / BM, 256, 0, stream>>>(bufs[1], wcls_bf, b_cls, out);
}